// Round 1
// baseline (288.862 us; speedup 1.0000x reference)
//
#include <hip/hip_runtime.h>
#include <hip/hip_bf16.h>
#include <stdint.h>

// Problem constants
#define B_SZ   8192
#define S_DIM  256
#define A_DIM  64
#define IN_DIM 320      // S + A
#define H_DIM  1024
#define E_NUM  8
#define OUT_DIM 257     // S + 1
#define TILE_M 128
#define MAXT   (B_SZ / TILE_M + E_NUM)   // 72 — worst-case padded tile count

typedef __bf16 bf16x8 __attribute__((ext_vector_type(8)));
typedef float  f32x4  __attribute__((ext_vector_type(4)));

typedef unsigned int __attribute__((address_space(1))) as1_uint;
typedef unsigned int __attribute__((address_space(3))) as3_uint;

__device__ __forceinline__ void gload_lds16(const void* g, void* l) {
    // async global->LDS, 16B/lane; LDS dest is wave-uniform base + lane*16
    __builtin_amdgcn_global_load_lds((const as1_uint*)g, (as3_uint*)l, 16, 0, 0);
}

__device__ __forceinline__ unsigned short f2bf(float f) {
    unsigned int u = __float_as_uint(f);
    return (unsigned short)((u + 0x7fffu + ((u >> 16) & 1u)) >> 16);  // RNE
}
__device__ __forceinline__ float bf2f(unsigned short h) {
    return __uint_as_float(((unsigned int)h) << 16);
}

// ---------------------------------------------------------------------------
// x = concat(state, action) -> bf16 (B, 320). One float4 quad per thread.
__global__ void k_convert_x(const float* __restrict__ state,
                            const float* __restrict__ action,
                            unsigned short* __restrict__ xb) {
    int q = blockIdx.x * blockDim.x + threadIdx.x;   // quad id: b*80 + j
    if (q >= B_SZ * 80) return;
    int b = q / 80, j = q % 80;
    float4 v;
    if (j < 64) v = ((const float4*)state)[b * 64 + j];
    else        v = ((const float4*)action)[b * 16 + (j - 64)];
    ushort4 o;
    o.x = f2bf(v.x); o.y = f2bf(v.y); o.z = f2bf(v.z); o.w = f2bf(v.w);
    ((ushort4*)xb)[q] = o;
}

// ---------------------------------------------------------------------------
// (E, K, Nsrc) fp32  ->  (E, Ncols, K) bf16   (transpose so MFMA B-frag reads
// from LDS are contiguous ds_read_b128). 64x64 tiles via LDS, conflict-free pad.
__global__ void k_transconv(const float* __restrict__ src,
                            unsigned short* __restrict__ dst,
                            int K, int Nsrc, int Ncols, int tk, int tn) {
    __shared__ float tile[64][65];
    int bid = blockIdx.x;
    int e  = bid / (tk * tn);
    int r  = bid % (tk * tn);
    int kt = r / tn, nt = r % tn;
    int k0 = kt * 64, n0 = nt * 64;
    const float* s = src + (size_t)e * K * Nsrc;
    unsigned short* d = dst + (size_t)e * Ncols * K;
    int tx = threadIdx.x & 63, ty = threadIdx.x >> 6;   // blockDim 256
    for (int rr = ty; rr < 64; rr += 4)
        tile[rr][tx] = s[(size_t)(k0 + rr) * Nsrc + (n0 + tx)];
    __syncthreads();
    for (int rr = ty; rr < 64; rr += 4)
        d[(size_t)(n0 + rr) * K + (k0 + tx)] = f2bf(tile[tx][rr]);
}

// ---------------------------------------------------------------------------
// Bucket rows by expert; build static tile table (exactly MAXT entries).
__global__ void k_bucket(const int* __restrict__ idx,
                         int* __restrict__ order,
                         int* __restrict__ offs,
                         int* __restrict__ tile_e,
                         int* __restrict__ tile_p0,
                         int* __restrict__ tile_cnt) {
    __shared__ int cnt[E_NUM], base[E_NUM], cur[E_NUM];
    int tid = threadIdx.x;
    if (tid < E_NUM) cnt[tid] = 0;
    __syncthreads();
    for (int b = tid; b < B_SZ; b += blockDim.x) atomicAdd(&cnt[idx[b]], 1);
    __syncthreads();
    if (tid == 0) {
        int acc = 0;
        for (int e = 0; e < E_NUM; e++) {
            base[e] = acc; cur[e] = acc; offs[e] = acc; acc += cnt[e];
        }
        offs[E_NUM] = acc;
    }
    __syncthreads();
    for (int b = tid; b < B_SZ; b += blockDim.x) {
        int e = idx[b];
        int p = atomicAdd(&cur[e], 1);
        order[p] = b;
    }
    if (tid == 0) {
        int t = 0;
        for (int e = 0; e < E_NUM; e++)
            for (int s = 0; s < cnt[e]; s += TILE_M) {
                tile_e[t] = e;
                tile_p0[t] = base[e] + s;
                tile_cnt[t] = min(TILE_M, cnt[e] - s);
                t++;
            }
        for (; t < MAXT; t++) { tile_e[t] = 0; tile_p0[t] = 0; tile_cnt[t] = 0; }
    }
}

// ---------------------------------------------------------------------------
// Grouped GEMM: C[128 x 128] per block, BK=32, 4 waves each doing 4x4 of
// 16x16x32 bf16 MFMA. A: (rows, K) bf16 (gathered via order if GATHER).
// Wt: (E, NTOT, K) bf16 (N-major => B-frag reads contiguous).
// MODE 0: Hout[(p0+m)*NTOT + n] = bf16(relu(acc + bias))
// MODE 1: Out[row*256 + n] = state[row*256 + n] + acc + bias,  row = order[p0+m]
template <int K, bool GATHER, int MODE>
__global__ __launch_bounds__(256, 2)
void k_gemm(const unsigned short* __restrict__ Abase,
            const unsigned short* __restrict__ Wt,
            const float* __restrict__ bias, int bias_stride,
            unsigned short* __restrict__ Hout,
            float* __restrict__ Out, const float* __restrict__ state,
            const int* __restrict__ order,
            const int* __restrict__ tile_e, const int* __restrict__ tile_p0,
            const int* __restrict__ tile_cnt, int NTOT) {
    int t = blockIdx.x;
    int cnt = tile_cnt[t];
    if (cnt == 0) return;
    int e = tile_e[t], p0 = tile_p0[t];
    int n0 = blockIdx.y * 128;
    int tid = threadIdx.x;
    int w = tid >> 6, lane = tid & 63;

    __shared__ __align__(16) unsigned short As[128 * 32];  // [row][k] row-major
    __shared__ __align__(16) unsigned short Bs[128 * 32];  // [n][k]   row-major

    // staging addresses: thread covers 16B at LDS byte tid*16 (+4096 for iter1)
    int rowA0 = tid >> 2;               // 0..63
    const unsigned short* aptr[2];
#pragma unroll
    for (int it = 0; it < 2; it++) {
        int rm = rowA0 + it * 64;
        int rc = rm < cnt ? rm : (cnt - 1);           // clamp (dup rows, masked later)
        int ar = GATHER ? order[p0 + rc] : (p0 + rc);
        aptr[it] = Abase + (size_t)ar * K + ((tid & 3) * 8);
    }
    const unsigned short* wptr0 =
        Wt + (size_t)e * NTOT * K + (size_t)(n0 + rowA0) * K + ((tid & 3) * 8);

    f32x4 acc[4][4] = {};
    int m_off = (w >> 1) * 64, n_off = (w & 1) * 64;
    const int fl_m = lane & 15;
    const int fl_k = (lane >> 4) * 8;

    for (int k0 = 0; k0 < K; k0 += 32) {
        __syncthreads();   // previous iter's LDS reads done before overwrite
        gload_lds16(aptr[0] + k0, (char*)As + tid * 16);
        gload_lds16(aptr[1] + k0, (char*)As + tid * 16 + 4096);
        gload_lds16(wptr0 + k0, (char*)Bs + tid * 16);
        gload_lds16(wptr0 + (size_t)64 * K + k0, (char*)Bs + tid * 16 + 4096);
        __syncthreads();   // drains vmcnt (global_load_lds) + lgkm

        bf16x8 af[4], bfr[4];
#pragma unroll
        for (int i = 0; i < 4; i++) {
            af[i]  = *(const bf16x8*)&As[(m_off + i * 16 + fl_m) * 32 + fl_k];
            bfr[i] = *(const bf16x8*)&Bs[(n_off + i * 16 + fl_m) * 32 + fl_k];
        }
#pragma unroll
        for (int mi = 0; mi < 4; mi++)
#pragma unroll
            for (int ni = 0; ni < 4; ni++)
                acc[mi][ni] = __builtin_amdgcn_mfma_f32_16x16x32_bf16(
                    af[mi], bfr[ni], acc[mi][ni], 0, 0, 0);
    }

    // epilogue: C/D mapping col = lane&15, row = (lane>>4)*4 + reg
    int col = lane & 15, rq = lane >> 4;
#pragma unroll
    for (int ni = 0; ni < 4; ni++) {
        int n = n0 + n_off + ni * 16 + col;
        float bv = bias[e * bias_stride + n];
#pragma unroll
        for (int mi = 0; mi < 4; mi++) {
#pragma unroll
            for (int r = 0; r < 4; r++) {
                int m = m_off + mi * 16 + rq * 4 + r;
                if (m < cnt) {
                    float v = acc[mi][ni][r] + bv;
                    if (MODE == 0) {
                        v = fmaxf(v, 0.f);
                        Hout[(size_t)(p0 + m) * NTOT + n] = f2bf(v);
                    } else {
                        int row = order[p0 + m];
                        size_t o = (size_t)row * 256 + n;
                        Out[o] = state[o] + v;
                    }
                }
            }
        }
    }
}

// ---------------------------------------------------------------------------
// reward[b] = h2[p] . W3[e][:,256] + b3[e][256]   (one wave per row)
__global__ void k_reward(const unsigned short* __restrict__ h2,
                         const float* __restrict__ W3,
                         const float* __restrict__ b3,
                         const int* __restrict__ order,
                         const int* __restrict__ offs,
                         float* __restrict__ out_reward) {
    int gw = (blockIdx.x * blockDim.x + threadIdx.x) >> 6;
    int lane = threadIdx.x & 63;
    if (gw >= B_SZ) return;
    int p = gw;
    int e = 0;
#pragma unroll
    for (int q = 1; q < E_NUM; q++)
        if (p >= offs[q]) e = q;
    const unsigned short* hr = h2 + (size_t)p * H_DIM;
    const float* wc = W3 + (size_t)e * H_DIM * OUT_DIM + 256;
    float acc = 0.f;
#pragma unroll
    for (int i = 0; i < 16; i++) {
        int k = lane + i * 64;
        acc += bf2f(hr[k]) * wc[(size_t)k * OUT_DIM];
    }
#pragma unroll
    for (int s = 32; s > 0; s >>= 1) acc += __shfl_down(acc, s, 64);
    if (lane == 0) out_reward[order[p]] = acc + b3[e * OUT_DIM + 256];
}

// ---------------------------------------------------------------------------
extern "C" void kernel_launch(void* const* d_in, const int* in_sizes, int n_in,
                              void* d_out, int out_size, void* d_ws, size_t ws_size,
                              hipStream_t stream) {
    const float* state  = (const float*)d_in[0];
    const float* action = (const float*)d_in[1];
    const int*   idx    = (const int*)d_in[2];
    const float* W1     = (const float*)d_in[3];
    const float* b1     = (const float*)d_in[4];
    const float* W2     = (const float*)d_in[5];
    const float* b2     = (const float*)d_in[6];
    const float* W3     = (const float*)d_in[7];
    const float* b3     = (const float*)d_in[8];
    float* out = (float*)d_out;

    char* ws = (char*)d_ws;
    size_t off = 0;
    auto alloc = [&](size_t bytes) -> void* {
        void* p = ws + off;
        off = (off + bytes + 255) & ~(size_t)255;
        return p;
    };
    unsigned short* xb  = (unsigned short*)alloc((size_t)B_SZ * IN_DIM * 2);
    unsigned short* w1t = (unsigned short*)alloc((size_t)E_NUM * H_DIM * IN_DIM * 2);
    unsigned short* w2t = (unsigned short*)alloc((size_t)E_NUM * H_DIM * H_DIM * 2);
    unsigned short* w3t = (unsigned short*)alloc((size_t)E_NUM * 256 * H_DIM * 2);
    unsigned short* h1  = (unsigned short*)alloc((size_t)B_SZ * H_DIM * 2);
    unsigned short* h2  = (unsigned short*)alloc((size_t)B_SZ * H_DIM * 2);
    int* order    = (int*)alloc(B_SZ * 4);
    int* offs     = (int*)alloc(16 * 4);
    int* tile_e   = (int*)alloc(MAXT * 4);
    int* tile_p0  = (int*)alloc(MAXT * 4);
    int* tile_cnt = (int*)alloc(MAXT * 4);

    // conversions + bucketing
    k_convert_x<<<(B_SZ * 80 + 255) / 256, 256, 0, stream>>>(state, action, xb);
    k_transconv<<<E_NUM * 5 * 16, 256, 0, stream>>>(W1, w1t, IN_DIM, H_DIM, H_DIM, 5, 16);
    k_transconv<<<E_NUM * 16 * 16, 256, 0, stream>>>(W2, w2t, H_DIM, H_DIM, H_DIM, 16, 16);
    k_transconv<<<E_NUM * 16 * 4, 256, 0, stream>>>(W3, w3t, H_DIM, OUT_DIM, 256, 16, 4);
    k_bucket<<<1, 256, 0, stream>>>(idx, order, offs, tile_e, tile_p0, tile_cnt);

    // grouped GEMM MLP (only the selected expert per row)
    dim3 g12(MAXT, H_DIM / 128);   // 72 x 8
    k_gemm<IN_DIM, true, 0><<<g12, 256, 0, stream>>>(
        xb, w1t, b1, H_DIM, h1, nullptr, nullptr, order, tile_e, tile_p0, tile_cnt, H_DIM);
    k_gemm<H_DIM, false, 0><<<g12, 256, 0, stream>>>(
        h1, w2t, b2, H_DIM, h2, nullptr, nullptr, order, tile_e, tile_p0, tile_cnt, H_DIM);
    dim3 g3(MAXT, 2);              // 72 x 2  (N = 256 delta cols)
    k_gemm<H_DIM, false, 1><<<g3, 256, 0, stream>>>(
        h2, w3t, b3, OUT_DIM, nullptr, out, state, order, tile_e, tile_p0, tile_cnt, 256);

    // reward column
    k_reward<<<(B_SZ * 64) / 256, 256, 0, stream>>>(
        h2, W3, b3, order, offs, out + (size_t)B_SZ * 256);
}

// Round 2
// 225.010 us; speedup vs baseline: 1.2838x; 1.2838x over previous
//
#include <hip/hip_runtime.h>
#include <stdint.h>

// Problem constants
#define B_SZ   8192
#define IN_DIM 320      // S + A
#define H_DIM  1024
#define E_NUM  8
#define OUT_DIM 257     // S + 1
#define TM     64
#define MAXT   (B_SZ / TM + E_NUM)   // 136 — worst-case M-tile count

typedef __bf16 bf16x8 __attribute__((ext_vector_type(8)));
typedef float  f32x4  __attribute__((ext_vector_type(4)));

typedef unsigned int __attribute__((address_space(1))) as1_uint;
typedef unsigned int __attribute__((address_space(3))) as3_uint;

__device__ __forceinline__ void gload_lds16(const void* g, void* l) {
    // async global->LDS, 16B/lane; LDS dest is wave-uniform base + lane*16
    __builtin_amdgcn_global_load_lds((const as1_uint*)g, (as3_uint*)l, 16, 0, 0);
}

__device__ __forceinline__ unsigned short f2bf(float f) {
    unsigned int u = __float_as_uint(f);
    return (unsigned short)((u + 0x7fffu + ((u >> 16) & 1u)) >> 16);  // RNE
}

// ---------------------------------------------------------------------------
// Uber prep kernel: block 0 = bucket rows by expert (sharded LDS atomics) +
// tile table; then x-concat/bf16-convert; then three transpose-converts
// (E,K,Nsrc) f32 -> (E,Ncols,K) bf16; then W3 reward-column extract into
// w3t row 256 (w3t has 320 rows; rows 257..319 are never written — their
// MFMA results are discarded in the gemm3 epilogue).
__global__ __launch_bounds__(256)
void k_prep(const float* __restrict__ state, const float* __restrict__ action,
            const int* __restrict__ idx,
            const float* __restrict__ W1, const float* __restrict__ W2,
            const float* __restrict__ W3,
            unsigned short* __restrict__ xb, unsigned short* __restrict__ w1t,
            unsigned short* __restrict__ w2t, unsigned short* __restrict__ w3t,
            int* __restrict__ order, int* __restrict__ te,
            int* __restrict__ tp0, int* __restrict__ tcnt) {
    __shared__ float tile[64][65];
    __shared__ int scnt[16][E_NUM];
    int bid = blockIdx.x, tid = threadIdx.x;

    if (bid == 0) {
        // ---- bucket ----
        int shard = tid & 15;
        if (tid < 128) ((int*)scnt)[tid] = 0;
        __syncthreads();
        for (int b = tid; b < B_SZ; b += 256) atomicAdd(&scnt[shard][idx[b]], 1);
        __syncthreads();
        if (tid == 0) {
            int pos = 0, tt = 0;
            for (int e = 0; e < E_NUM; e++) {
                int start = pos;
                for (int s = 0; s < 16; s++) { int c = scnt[s][e]; scnt[s][e] = pos; pos += c; }
                int tot = pos - start;
                for (int st = 0; st < tot; st += TM) {
                    te[tt] = e; tp0[tt] = start + st; tcnt[tt] = min(TM, tot - st); tt++;
                }
            }
            for (; tt < MAXT; tt++) { te[tt] = 0; tp0[tt] = 0; tcnt[tt] = 0; }
        }
        __syncthreads();
        for (int b = tid; b < B_SZ; b += 256) {
            int e = idx[b];
            int p = atomicAdd(&scnt[shard][e], 1);
            order[p] = b;
        }
        return;
    }

    if (bid <= 2560) {
        // ---- x = concat(state, action) -> bf16 ----  (2560 blocks, exact)
        int q = (bid - 1) * 256 + tid;   // quad id: b*80 + j
        int b = q / 80, j = q % 80;
        float4 v = (j < 64) ? ((const float4*)state)[b * 64 + j]
                            : ((const float4*)action)[b * 16 + (j - 64)];
        ushort4 o;
        o.x = f2bf(v.x); o.y = f2bf(v.y); o.z = f2bf(v.z); o.w = f2bf(v.w);
        ((ushort4*)xb)[q] = o;
        return;
    }

    if (bid < 5761) {
        // ---- transpose-convert: 64x64 tiles via LDS ----
        int e, kt, nt, K, Nsrc, dstRows;
        const float* src; unsigned short* dst;
        if (bid < 3201) {        // W1: (8,320,1024) -> (8,1024,320); 80 tiles/e
            int r = bid - 2561; e = r / 80; int m = r % 80; kt = m / 16; nt = m % 16;
            K = IN_DIM; Nsrc = H_DIM; dstRows = H_DIM; src = W1; dst = w1t;
        } else if (bid < 5249) { // W2: (8,1024,1024) -> (8,1024,1024); 256 tiles/e
            int r = bid - 3201; e = r / 256; int m = r % 256; kt = m / 16; nt = m % 16;
            K = H_DIM; Nsrc = H_DIM; dstRows = H_DIM; src = W2; dst = w2t;
        } else {                 // W3: (8,1024,257) -> rows 0..255 of (8,320,1024)
            int r = bid - 5249; e = r / 64; int m = r % 64; kt = m / 4; nt = m % 4;
            K = H_DIM; Nsrc = OUT_DIM; dstRows = 320; src = W3; dst = w3t;
        }
        int k0 = kt * 64, n0 = nt * 64;
        const float* s = src + (size_t)e * K * Nsrc;
        unsigned short* d = dst + (size_t)e * dstRows * K;
        int tx = tid & 63, ty = tid >> 6;
        for (int rr = ty; rr < 64; rr += 4)
            tile[rr][tx] = s[(size_t)(k0 + rr) * Nsrc + (n0 + tx)];
        __syncthreads();
        for (int rr = ty; rr < 64; rr += 4)
            d[(size_t)(n0 + rr) * K + (k0 + tx)] = f2bf(tile[tx][rr]);
        return;
    }

    // ---- W3 reward column -> w3t row 256 ----  (32 blocks)
    int i = (bid - 5761) * 256 + tid;        // 8192 = 8 experts x 1024 k
    int e = i >> 10, k = i & 1023;
    w3t[((size_t)e * 320 + 256) * H_DIM + k] =
        f2bf(W3[((size_t)e * H_DIM + k) * OUT_DIM + 256]);
}

// ---------------------------------------------------------------------------
// Grouped GEMM, software-pipelined (2-stage LDS dbuf), TM=64 rows per block.
// 4 waves side-by-side in N: wave w computes 64 x WN (TN = 4*WN).
// LDS layout is XOR-swizzled: LDS slot (row, chunk c) holds global 16B chunk
// (c ^ ((row>>1)&3)) — makes the 16-lane b128 fragment reads 2-way (free).
// Wt: (E, wtRows, K) bf16, N-major.
// MODE 0: Hout[(p0+m)*1024 + n] = bf16(relu(acc + bias))
// MODE 1 (layer 3 + fused reward): n<256 -> Out[row*256+n] = state + acc + b;
//         n==256 -> Out[B*256 + row] = acc + b;  n>256 -> discard.
template <int K, int TN, int WN, bool GATHER, int MODE>
__global__ __launch_bounds__(256, 2)
void k_gemm(const unsigned short* __restrict__ Abase,
            const unsigned short* __restrict__ Wt, int wtRows,
            const float* __restrict__ bias, int bstride,
            unsigned short* __restrict__ Hout,
            float* __restrict__ Out, const float* __restrict__ state,
            const int* __restrict__ order,
            const int* __restrict__ te, const int* __restrict__ tp0,
            const int* __restrict__ tcnt) {
    constexpr int NI  = K / 32;
    constexpr int NF  = WN / 16;
    constexpr int ABY = 64 * 64;          // A stage bytes (64 rows x 64B)
    constexpr int BBY = TN * 64;          // B stage bytes
    constexpr int STG = ABY + BBY;
    __shared__ __align__(16) char lds[2 * STG];

    int t = blockIdx.x;
    int cnt = tcnt[t];
    if (cnt == 0) return;
    int e = te[t], p0 = tp0[t];
    int n0 = blockIdx.y * TN;
    int tid = threadIdx.x;
    int w = tid >> 6, lane = tid & 63;

    // staging source pointers (thread fills LDS slot row=tid>>2, chunk=tid&3;
    // fetches global chunk (tid&3) ^ swizzle(row))
    int r  = tid >> 2;
    int cg = (tid & 3) ^ ((r >> 1) & 3);
    int rc = r < cnt ? r : cnt - 1;                 // clamp; masked in epilogue
    long arow = GATHER ? order[p0 + rc] : (p0 + rc);
    const unsigned short* aP = Abase + (size_t)arow * K + cg * 8;
    const unsigned short* bP = Wt + ((size_t)e * wtRows + n0 + r) * K + cg * 8;

    auto stage = [&](int k0, int sb) {
        gload_lds16(aP + k0, lds + sb + tid * 16);
        gload_lds16(bP + k0, lds + sb + ABY + tid * 16);
        if (TN == 128)
            gload_lds16(bP + (size_t)64 * K + k0, lds + sb + ABY + 4096 + tid * 16);
    };

    f32x4 acc[4][NF];
#pragma unroll
    for (int i = 0; i < 4; i++)
#pragma unroll
        for (int j = 0; j < NF; j++) acc[i][j] = (f32x4)0.f;

    const int fm   = lane & 15;
    const int kc   = lane >> 4;
    const int koff = ((kc ^ ((fm >> 1) & 3)) * 8);  // swizzled k-chunk offset

    stage(0, 0);
    for (int it = 0; it < NI; ++it) {
        __syncthreads();                             // drains tile-it loads (issued 1 iter ago)
        if (it + 1 < NI) stage((it + 1) * 32, ((it + 1) & 1) * STG);
        const unsigned short* As = (const unsigned short*)(lds + (it & 1) * STG);
        const unsigned short* Bs = As + ABY / 2;

        bf16x8 af[4], bf[NF];
#pragma unroll
        for (int i = 0; i < 4; i++)
            af[i] = *(const bf16x8*)&As[(i * 16 + fm) * 32 + koff];
#pragma unroll
        for (int j = 0; j < NF; j++)
            bf[j] = *(const bf16x8*)&Bs[(w * WN + j * 16 + fm) * 32 + koff];
#pragma unroll
        for (int i = 0; i < 4; i++)
#pragma unroll
            for (int j = 0; j < NF; j++)
                acc[i][j] = __builtin_amdgcn_mfma_f32_16x16x32_bf16(
                    af[i], bf[j], acc[i][j], 0, 0, 0);
    }

    // epilogue: C/D mapping col = lane&15, row = (lane>>4)*4 + reg
    int col = lane & 15, rq = lane >> 4;
#pragma unroll
    for (int j = 0; j < NF; j++) {
        int n = n0 + w * WN + j * 16 + col;
        float bv = (MODE == 0) ? bias[e * bstride + n]
                               : ((n <= 256) ? bias[e * bstride + n] : 0.f);
#pragma unroll
        for (int i = 0; i < 4; i++) {
#pragma unroll
            for (int rr = 0; rr < 4; rr++) {
                int m = i * 16 + rq * 4 + rr;
                if (m < cnt) {
                    float v = acc[i][j][rr] + bv;
                    if (MODE == 0) {
                        Hout[(size_t)(p0 + m) * H_DIM + n] = f2bf(fmaxf(v, 0.f));
                    } else {
                        int row = order[p0 + m];
                        if (n < 256) {
                            size_t o = (size_t)row * 256 + n;
                            Out[o] = state[o] + v;
                        } else if (n == 256) {
                            Out[(size_t)B_SZ * 256 + row] = v;   // reward
                        }
                    }
                }
            }
        }
    }
}

// ---------------------------------------------------------------------------
extern "C" void kernel_launch(void* const* d_in, const int* in_sizes, int n_in,
                              void* d_out, int out_size, void* d_ws, size_t ws_size,
                              hipStream_t stream) {
    const float* state  = (const float*)d_in[0];
    const float* action = (const float*)d_in[1];
    const int*   idx    = (const int*)d_in[2];
    const float* W1     = (const float*)d_in[3];
    const float* b1     = (const float*)d_in[4];
    const float* W2     = (const float*)d_in[5];
    const float* b2     = (const float*)d_in[6];
    const float* W3     = (const float*)d_in[7];
    const float* b3     = (const float*)d_in[8];
    float* out = (float*)d_out;

    char* ws = (char*)d_ws;
    size_t off = 0;
    auto alloc = [&](size_t bytes) -> void* {
        void* p = ws + off;
        off = (off + bytes + 255) & ~(size_t)255;
        return p;
    };
    unsigned short* xb  = (unsigned short*)alloc((size_t)B_SZ * IN_DIM * 2);
    unsigned short* w1t = (unsigned short*)alloc((size_t)E_NUM * H_DIM * IN_DIM * 2);
    unsigned short* w2t = (unsigned short*)alloc((size_t)E_NUM * H_DIM * H_DIM * 2);
    unsigned short* w3t = (unsigned short*)alloc((size_t)E_NUM * 320 * H_DIM * 2);
    unsigned short* h1  = (unsigned short*)alloc((size_t)B_SZ * H_DIM * 2);
    unsigned short* h2  = (unsigned short*)alloc((size_t)B_SZ * H_DIM * 2);
    int* order = (int*)alloc(B_SZ * 4);
    int* te    = (int*)alloc(MAXT * 4);
    int* tp0   = (int*)alloc(MAXT * 4);
    int* tcnt  = (int*)alloc(MAXT * 4);

    // prep: bucket + convert x + transpose-convert W1/W2/W3 + reward column
    k_prep<<<5793, 256, 0, stream>>>(state, action, idx, W1, W2, W3,
                                     xb, w1t, w2t, w3t, order, te, tp0, tcnt);

    // layer 1: (B,320) x (320,1024) grouped, gather rows
    k_gemm<IN_DIM, 128, 32, true, 0><<<dim3(MAXT, 8), 256, 0, stream>>>(
        xb, w1t, H_DIM, b1, H_DIM, h1, nullptr, nullptr, order, te, tp0, tcnt);
    // layer 2: (B,1024) x (1024,1024)
    k_gemm<H_DIM, 128, 32, false, 0><<<dim3(MAXT, 8), 256, 0, stream>>>(
        h1, w2t, H_DIM, b2, H_DIM, h2, nullptr, nullptr, order, te, tp0, tcnt);
    // layer 3 + fused reward: (B,1024) x (1024,320-padded), N tiles of 64
    k_gemm<H_DIM, 64, 16, false, 1><<<dim3(MAXT, 5), 256, 0, stream>>>(
        h2, w3t, 320, b3, OUT_DIM, nullptr, out, state, order, te, tp0, tcnt);
}